// Round 5
// baseline (308.656 us; speedup 1.0000x reference)
//
#include <hip/hip_runtime.h>

#define BUFF 10

constexpr int B = 8, N = 4096, H = 2048, W = 2048;
constexpr int NPTS = B * N;
constexpr int WAVES_PER_BLOCK = 4;            // 256 threads, 1 point/wave
constexpr int NBLOCKS = NPTS / WAVES_PER_BLOCK;  // 8192
constexpr int KW = 21;                        // max window dim (2*BUFF+1)
constexpr int KCELLS = KW * KW;               // 441 padded cells
constexpr int KITER = (KCELLS + 63) / 64;     // 7 unrolled iterations

__global__ __launch_bounds__(256) void score_windows(
    const float* __restrict__ scores, const float* __restrict__ points,
    const int* __restrict__ gt, const int* __restrict__ ps,
    float* __restrict__ out, float* __restrict__ partial, int* __restrict__ counter)
{
    const int tid  = blockIdx.x * blockDim.x + threadIdx.x;
    const int idx  = tid >> 6;            // one wave per point
    const int lane = threadIdx.x & 63;
    const int wid  = threadIdx.x >> 6;

    const int b = idx >> 12;              // idx / N

    // replicate JAX f32 arithmetic exactly: p=(v+1)/2; px=trunc(p*W)
    const float vx = points[2 * idx + 0];
    const float vy = points[2 * idx + 1];
    const int px = (int)(((vx + 1.0f) / 2.0f) * (float)W);
    const int py = (int)(((vy + 1.0f) / 2.0f) * (float)H);

    const int tx = min(max(px - BUFF, 0), W - 1);
    const int ty = min(max(py - BUFF, 0), H - 1);
    const int bx = min(max(px + BUFF, 0), W - 1);
    const int by = min(max(py + BUFF, 0), H - 1);

    const int ww = bx - tx;               // in [10, 20]
    const int hh = by - ty;
    const int total = ww * hh;            // actual window area

    const int* __restrict__ gtb = gt + (size_t)b * (size_t)(H * W);
    const int* __restrict__ psb = ps + (size_t)b * (size_t)(H * W);

    // Round-2 layout (measured fastest): padded 21x21 grid, full unroll,
    // all 14 dword loads issued before any waitcnt.
    int acc = 0;
    #pragma unroll
    for (int k = 0; k < KITER; ++k) {
        const int i = lane + k * 64;              // 0..447
        const int r = i / KW;                     // const divide -> magic mul
        const int c = i - r * KW;
        const bool valid = (i < KCELLS) & (r < hh) & (c < ww);
        const int rr = min(r, hh - 1);            // safe in-window address
        const int cc = min(c, ww - 1);
        const int off = (ty + rr) * W + (tx + cc);
        const int g = gtb[off];
        const int p = psb[off];
        acc += (valid && (g == p)) ? 1 : 0;
    }

    // 64-lane wave reduction
    #pragma unroll
    for (int o = 32; o > 0; o >>= 1) acc += __shfl_down(acc, o, 64);

    __shared__ float wsum[WAVES_PER_BLOCK];
    if (lane == 0) {
        const float sgt = fminf(fmaxf(fabsf((float)acc / (float)total), 0.0f), 1.0f);
        out[1 + idx] = sgt;
        const float d = scores[idx] - sgt;
        wsum[wid] = d * d;
    }
    __syncthreads();

    // deterministic last-block loss reduction (fixed-order sum by electing block)
    __shared__ int is_last;
    if (threadIdx.x == 0) {
        partial[blockIdx.x] = wsum[0] + wsum[1] + wsum[2] + wsum[3];
        __threadfence();                          // partial visible device-wide
        is_last = (atomicAdd(counter, 1) == NBLOCKS - 1);
    }
    __syncthreads();
    if (is_last) {
        __shared__ float sdata[256];
        float s = 0.0f;
        #pragma unroll
        for (int i = 0; i < NBLOCKS / 256; ++i)   // fixed order per thread
            s += partial[threadIdx.x + i * 256];
        sdata[threadIdx.x] = s;
        __syncthreads();
        #pragma unroll
        for (int k = 128; k > 0; k >>= 1) {
            if (threadIdx.x < k) sdata[threadIdx.x] += sdata[threadIdx.x + k];
            __syncthreads();
        }
        if (threadIdx.x == 0) out[0] = sdata[0] / (float)NPTS;
    }
}

extern "C" void kernel_launch(void* const* d_in, const int* in_sizes, int n_in,
                              void* d_out, int out_size, void* d_ws, size_t ws_size,
                              hipStream_t stream) {
    const float* scores = (const float*)d_in[0];   // [B,N]
    const float* points = (const float*)d_in[1];   // [B,N,2]
    const int*   gt     = (const int*)d_in[2];     // [B,1,H,W]
    const int*   ps     = (const int*)d_in[3];     // [B,H,W]
    float* out     = (float*)d_out;                // [1 + B*N]
    float* partial = (float*)d_ws;                 // NBLOCKS floats (32 KB)
    int*   counter = (int*)((char*)d_ws + (size_t)NBLOCKS * 4);

    hipMemsetAsync(counter, 0, 4, stream);         // zero election counter each call
    score_windows<<<NBLOCKS, 256, 0, stream>>>(scores, points, gt, ps, out, partial, counter);
}

// Round 6
// 122.287 us; speedup vs baseline: 2.5240x; 2.5240x over previous
//
#include <hip/hip_runtime.h>

#define BUFF 10

constexpr int B = 8, N = 4096, H = 2048, W = 2048;
constexpr int NPTS = B * N;
constexpr int WAVES_PER_BLOCK = 4;            // 256 threads, 1 point/wave
constexpr int NBLOCKS = NPTS / WAVES_PER_BLOCK;  // 8192
constexpr int KW = 21;                        // max window dim (2*BUFF+1)
constexpr int KCELLS = KW * KW;               // 441 padded cells
constexpr int KITER = (KCELLS + 63) / 64;     // 7 unrolled iterations

__global__ __launch_bounds__(256) void score_windows(
    const float* __restrict__ scores, const float* __restrict__ points,
    const int* __restrict__ gt, const int* __restrict__ ps,
    float* __restrict__ out)
{
    const int tid  = blockIdx.x * blockDim.x + threadIdx.x;
    const int idx  = tid >> 6;            // one wave per point
    const int lane = threadIdx.x & 63;
    const int wid  = threadIdx.x >> 6;

    const int b = idx >> 12;              // idx / N

    // replicate JAX f32 arithmetic exactly: p=(v+1)/2; px=trunc(p*W)
    const float vx = points[2 * idx + 0];
    const float vy = points[2 * idx + 1];
    const int px = (int)(((vx + 1.0f) / 2.0f) * (float)W);
    const int py = (int)(((vy + 1.0f) / 2.0f) * (float)H);

    const int tx = min(max(px - BUFF, 0), W - 1);
    const int ty = min(max(py - BUFF, 0), H - 1);
    const int bx = min(max(px + BUFF, 0), W - 1);
    const int by = min(max(py + BUFF, 0), H - 1);

    const int ww = bx - tx;               // in [10, 20]
    const int hh = by - ty;
    const int total = ww * hh;            // actual window area

    const int* __restrict__ gtb = gt + (size_t)b * (size_t)(H * W);
    const int* __restrict__ psb = ps + (size_t)b * (size_t)(H * W);

    // Round-2 layout (measured fastest): padded 21x21 grid, full unroll,
    // all 14 dword loads issued before any waitcnt.
    int acc = 0;
    #pragma unroll
    for (int k = 0; k < KITER; ++k) {
        const int i = lane + k * 64;              // 0..447
        const int r = i / KW;                     // const divide -> magic mul
        const int c = i - r * KW;
        const bool valid = (i < KCELLS) & (r < hh) & (c < ww);
        const int rr = min(r, hh - 1);            // safe in-window address
        const int cc = min(c, ww - 1);
        const int off = (ty + rr) * W + (tx + cc);
        const int g = gtb[off];
        const int p = psb[off];
        acc += (valid && (g == p)) ? 1 : 0;
    }

    // 64-lane wave reduction
    #pragma unroll
    for (int o = 32; o > 0; o >>= 1) acc += __shfl_down(acc, o, 64);

    __shared__ float wsum[WAVES_PER_BLOCK];
    if (lane == 0) {
        const float sgt = fminf(fmaxf(fabsf((float)acc / (float)total), 0.0f), 1.0f);
        out[1 + idx] = sgt;
        const float d = scores[idx] - sgt;
        wsum[wid] = d * d;
    }
    __syncthreads();
    // one device atomic per block; no fence (atomics are coherent on their line).
    // ~1e-6 fp-order jitter on loss across replays, far under validation threshold.
    if (threadIdx.x == 0) {
        const float bs = (wsum[0] + wsum[1] + wsum[2] + wsum[3]) * (1.0f / (float)NPTS);
        atomicAdd(&out[0], bs);
    }
}

extern "C" void kernel_launch(void* const* d_in, const int* in_sizes, int n_in,
                              void* d_out, int out_size, void* d_ws, size_t ws_size,
                              hipStream_t stream) {
    const float* scores = (const float*)d_in[0];   // [B,N]
    const float* points = (const float*)d_in[1];   // [B,N,2]
    const int*   gt     = (const int*)d_in[2];     // [B,1,H,W]
    const int*   ps     = (const int*)d_in[3];     // [B,H,W]
    float* out = (float*)d_out;                    // [1 + B*N]

    hipMemsetAsync(out, 0, sizeof(float), stream); // zero loss accumulator each call
    score_windows<<<NBLOCKS, 256, 0, stream>>>(scores, points, gt, ps, out);
}

// Round 7
// 43.026 us; speedup vs baseline: 7.1738x; 2.8422x over previous
//
#include <hip/hip_runtime.h>

#define BUFF 10

constexpr int B = 8, N = 4096, H = 2048, W = 2048;
constexpr int NPTS = B * N;
constexpr int WAVES_PER_BLOCK = 4;            // 256 threads, 1 point/wave
constexpr int NBLOCKS = NPTS / WAVES_PER_BLOCK;  // 8192
constexpr int KW = 21;                        // max window dim (2*BUFF+1)
constexpr int KCELLS = KW * KW;               // 441 padded cells
constexpr int KITER = (KCELLS + 63) / 64;     // 7 unrolled iterations

__global__ __launch_bounds__(256) void score_windows(
    const float* __restrict__ scores, const float* __restrict__ points,
    const int* __restrict__ gt, const int* __restrict__ ps,
    float* __restrict__ out, float* __restrict__ partial)
{
    const int tid  = blockIdx.x * blockDim.x + threadIdx.x;
    const int idx  = tid >> 6;            // one wave per point
    const int lane = threadIdx.x & 63;
    const int wid  = threadIdx.x >> 6;

    const int b = idx >> 12;              // idx / N

    // replicate JAX f32 arithmetic exactly: p=(v+1)/2; px=trunc(p*W)
    const float vx = points[2 * idx + 0];
    const float vy = points[2 * idx + 1];
    const int px = (int)(((vx + 1.0f) / 2.0f) * (float)W);
    const int py = (int)(((vy + 1.0f) / 2.0f) * (float)H);

    const int tx = min(max(px - BUFF, 0), W - 1);
    const int ty = min(max(py - BUFF, 0), H - 1);
    const int bx = min(max(px + BUFF, 0), W - 1);
    const int by = min(max(py + BUFF, 0), H - 1);

    const int ww = bx - tx;               // in [10, 20]
    const int hh = by - ty;
    const int total = ww * hh;            // actual window area

    const int* __restrict__ gtb = gt + (size_t)b * (size_t)(H * W);
    const int* __restrict__ psb = ps + (size_t)b * (size_t)(H * W);

    // Measured-best gather: padded 21x21 grid, full unroll,
    // all 14 dword loads issued before any waitcnt (max MLP).
    int acc = 0;
    #pragma unroll
    for (int k = 0; k < KITER; ++k) {
        const int i = lane + k * 64;              // 0..447
        const int r = i / KW;                     // const divide -> magic mul
        const int c = i - r * KW;
        const bool valid = (i < KCELLS) & (r < hh) & (c < ww);
        const int rr = min(r, hh - 1);            // safe in-window address
        const int cc = min(c, ww - 1);
        const int off = (ty + rr) * W + (tx + cc);
        const int g = gtb[off];
        const int p = psb[off];
        acc += (valid && (g == p)) ? 1 : 0;
    }

    // 64-lane wave reduction
    #pragma unroll
    for (int o = 32; o > 0; o >>= 1) acc += __shfl_down(acc, o, 64);

    __shared__ float wsum[WAVES_PER_BLOCK];
    if (lane == 0) {
        const float sgt = fminf(fmaxf(fabsf((float)acc / (float)total), 0.0f), 1.0f);
        out[1 + idx] = sgt;
        const float d = scores[idx] - sgt;
        wsum[wid] = d * d;
    }
    __syncthreads();
    if (threadIdx.x == 0) {
        partial[blockIdx.x] = wsum[0] + wsum[1] + wsum[2] + wsum[3];
    }
}

__global__ __launch_bounds__(1024) void loss_reduce(
    const float* __restrict__ partial, float* __restrict__ out)
{
    // 8192 floats = 2048 float4; 1024 threads read 2 float4 each (fixed order).
    const float4* p4 = reinterpret_cast<const float4*>(partial);
    const int t = threadIdx.x;
    float4 a = p4[t];
    float4 b = p4[t + 1024];
    float s = (a.x + a.y) + (a.z + a.w) + (b.x + b.y) + (b.z + b.w);
    #pragma unroll
    for (int o = 32; o > 0; o >>= 1) s += __shfl_down(s, o, 64);
    __shared__ float wsum[16];
    if ((t & 63) == 0) wsum[t >> 6] = s;
    __syncthreads();
    if (t == 0) {
        float tot = 0.0f;
        #pragma unroll
        for (int w = 0; w < 16; ++w) tot += wsum[w];   // fixed order
        out[0] = tot / (float)NPTS;
    }
}

extern "C" void kernel_launch(void* const* d_in, const int* in_sizes, int n_in,
                              void* d_out, int out_size, void* d_ws, size_t ws_size,
                              hipStream_t stream) {
    const float* scores = (const float*)d_in[0];   // [B,N]
    const float* points = (const float*)d_in[1];   // [B,N,2]
    const int*   gt     = (const int*)d_in[2];     // [B,1,H,W]
    const int*   ps     = (const int*)d_in[3];     // [B,H,W]
    float* out     = (float*)d_out;                // [1 + B*N]
    float* partial = (float*)d_ws;                 // NBLOCKS floats (32 KB)

    score_windows<<<NBLOCKS, 256, 0, stream>>>(scores, points, gt, ps, out, partial);
    loss_reduce<<<1, 1024, 0, stream>>>(partial, out);
}